// Round 18
// baseline (1201.966 us; speedup 1.0000x reference)
//
#include <hip/hip_runtime.h>
#include <stdint.h>

// SPIRiT CG reconstruction. Convs: single-product bf16 MFMA (W and X RN bf16),
// per-tap implicit GEMM M=16 c_out, N=16 pixels, K=32 = 16 c_in x {re,im}.
// R18: occupancy play — 6x16 tile, grid 1536 = 6 blocks/CU (R11-R17's 768 grid
// capped residency at 3 blocks/CU; ALL intra-kernel scheduling levers were
// null because only 18 waves/CU existed to hide latency). 384 threads = 6
// waves = 2 components x 3 row-pairs. No Wsh, no column barriers (R12's
// barrier-free W register ring from global/L2 was the best variant). LDS
// 21.5 KB -> 5 blocks resident = 30 waves/CU. launch_bounds(384,8) caps
// VGPR at 64. Vectorized complex epilogue via LDS acc exchange.

#define MM 384
#define NPIX (MM*MM)          // 147456
#define N2 (16*NPIX)
#define NRED 512
#define NCBLK 1536            // 64 row-tiles (6 rows) x 24 col-tiles (16 cols)

typedef __attribute__((ext_vector_type(8))) short short8;
typedef __attribute__((ext_vector_type(4))) float f32x4;
typedef unsigned int u32;

__device__ __forceinline__ float2 block_reduce2(float2 v) {
    #pragma unroll
    for (int off = 32; off > 0; off >>= 1) {
        v.x += __shfl_down(v.x, off);
        v.y += __shfl_down(v.y, off);
    }
    __shared__ float2 tmp[8];
    const int wid = threadIdx.x >> 6, lid = threadIdx.x & 63;
    if (lid == 0) tmp[wid] = v;
    __syncthreads();
    if (threadIdx.x == 0) {
        const int nw = blockDim.x >> 6;
        for (int i = 1; i < nw; ++i) { v.x += tmp[i].x; v.y += tmp[i].y; }
    }
    return v;
}

__device__ __forceinline__ u32 bf16rn(float f) {   // round-to-nearest-even bf16
    const u32 u = __float_as_uint(f);
    return (u + 0x7FFFu + ((u >> 16) & 1u)) >> 16;
}

// Weight fragments (RN bf16): [dir][slot=q*9+p][hf][lane64][4 u32]  (q-major)
// hf=0 rows: [Wr | -Wi] (-> real), hf=1 rows: [Wi | Wr] (-> imag);
// lane = co + 16*kgroup. Tap block = 2 KB (1 KB per hf).
__global__ void prep_weights(const float* __restrict__ kr, const float* __restrict__ ki,
                             u32* __restrict__ wbuf) {
    const int e = blockIdx.x * 256 + threadIdx.x;
    if (e >= 20736) return;    // 2 dir x 81 tap x 2 hf x 64 lane
    const int lane = e & 63;
    int r = e >> 6;
    const int hf = r & 1; r >>= 1;
    const int q = r % 9; r /= 9;
    const int p = r % 9; r /= 9;
    const int dir = r;
    const int co = lane & 15, g = lane >> 4;
    float vv[8];
    #pragma unroll
    for (int t = 0; t < 8; ++t) {
        const int kc = 8 * g + t;
        const int ci = kc & 15;
        const int isI = kc >> 4;
        int sidx;
        if (dir == 0) sidx = (q*9 + p)*256 + ci*16 + co;          // Wf[co,ci,p,q]=K[q,p,ci,co]
        else          sidx = ((8-q)*9 + (8-p))*256 + co*16 + ci;  // Wb = conj flip swap
        const float wr = kr[sidx];
        const float wi = (dir == 0) ? ki[sidx] : -ki[sidx];
        vv[t] = (hf == 0) ? (isI ? -wi : wr) : (isI ? wr : wi);
    }
    u32 pk[4];
    #pragma unroll
    for (int t = 0; t < 4; ++t) pk[t] = bf16rn(vv[2*t]) | (bf16rn(vv[2*t+1]) << 16);
    u32* o = wbuf + (size_t)(dir*162 + (q*9 + p)*2 + hf)*256 + lane*4;
    *(uint4*)o = make_uint4(pk[0], pk[1], pk[2], pk[3]);
}

__global__ void prep_fields(const float* __restrict__ ks, const float* __restrict__ prev,
                            float2* __restrict__ wsf, uint8_t* __restrict__ mask8) {
    const int pix = blockIdx.x * blockDim.x + threadIdx.x;
    if (pix >= NPIX) return;
    #pragma unroll
    for (int c = 0; c < 16; ++c) {
        const float krr = ks[(size_t)pix*32 + c];
        const float kii = ks[(size_t)pix*32 + c + 16];
        mask8[(size_t)c*NPIX + pix] = (krr != 0.f || kii != 0.f) ? 1 : 0;
        wsf[(size_t)c*NPIX + pix] = make_float2(prev[(size_t)pix*32 + c], prev[(size_t)pix*32 + c + 16]);
    }
}

// MODE 0: out = conv(x) - x
// MODE 1: out = conv(x) - x + (mask+am)*aux ; partial += out*conj(aux)
// MODE 2: out=out2 = mask*kk + am*z - (conv(x)-x) - (mask+am)*aux ; partial += |out|^2
template<int MODE>
__global__ __launch_bounds__(384, 8)
void conv9(const float2* __restrict__ x, const u32* __restrict__ Wd,
           float2* __restrict__ out, float2* __restrict__ out2,
           const float2* __restrict__ aux, const float* __restrict__ ks,
           const float* __restrict__ z, const uint8_t* __restrict__ mask8,
           const float* __restrict__ miu, float2* __restrict__ partials)
{
    __shared__ __align__(16) char Xs[14*24*64];   // 21504 B; reused for acc exchange
    const int t = threadIdx.x;
    const int bi0 = blockIdx.x;
    const int bi = (bi0 & 7) * 192 + (bi0 >> 3);  // XCD swizzle: 8-tile-row band/XCD
    const int i0 = (bi / 24) * 6;
    const int j0 = (bi % 24) * 16;
    const int w = t >> 6, lane = t & 63;
    const int hf = (w >= 3) ? 1 : 0;  // 0: real component, 1: imag component
    const int wr = w - 3*hf;          // row pair (rows 2wr, 2wr+1)
    const int m = lane & 15, g = lane >> 4;

    // ---- stage 14x24 slab (rows i0-4..i0+9, cols j0-4..j0+19), bf16 RN,
    //      64 B/px: 4 slots of 16B, content c stored at slot c ^ (col&3).
    if (t < 14*24) {
        const int col = t % 24, row = t / 24;
        const int row_g = i0 - 4 + row, col_g = j0 - 4 + col;
        const bool valid = ((unsigned)row_g < MM) && ((unsigned)col_g < MM);
        const float2* src = x + (size_t)row_g*MM + col_g;
        float2 v[16];
        #pragma unroll
        for (int ci = 0; ci < 16; ++ci)
            v[ci] = valid ? src[(size_t)ci*NPIX] : make_float2(0.f, 0.f);
        u32 c0[4], c1[4], c2[4], c3[4];
        #pragma unroll
        for (int j = 0; j < 4; ++j) {
            c0[j] = bf16rn(v[2*j].x)     | (bf16rn(v[2*j+1].x) << 16);
            c1[j] = bf16rn(v[8+2*j].x)   | (bf16rn(v[9+2*j].x) << 16);
            c2[j] = bf16rn(v[2*j].y)     | (bf16rn(v[2*j+1].y) << 16);
            c3[j] = bf16rn(v[8+2*j].y)   | (bf16rn(v[9+2*j].y) << 16);
        }
        const int k3 = col & 3;
        char* pb = Xs + (size_t)(row*24 + col)*64;
        *(uint4*)(pb + (((0 ^ k3)) << 4)) = make_uint4(c0[0], c0[1], c0[2], c0[3]);
        *(uint4*)(pb + (((1 ^ k3)) << 4)) = make_uint4(c1[0], c1[1], c1[2], c1[3]);
        *(uint4*)(pb + (((2 ^ k3)) << 4)) = make_uint4(c2[0], c2[1], c2[2], c2[3]);
        *(uint4*)(pb + (((3 ^ k3)) << 4)) = make_uint4(c3[0], c3[1], c3[2], c3[3]);
    }
    __syncthreads();

    f32x4 acc[2];
    acc[0] = (f32x4){0.f, 0.f, 0.f, 0.f};
    acc[1] = (f32x4){0.f, 0.f, 0.f, 0.f};

    // ---- 81 taps, q-outer / p-inner (unrolled 9). Wave owns rows 2wr,2wr+1,
    //      component hf. X ring-3, W ring-3 from global (L2-resident, the
    //      R12-verified pattern), compute-then-prefetch, NO column barriers.
    const char* wl = (const char*)Wd + (lane << 4) + (hf << 10);
    short8 WA, WB, WC, XA, XB, XC;

    #define LW(WS, TAP) do { WS = *(const short8*)(wl + (size_t)(TAP)*2048); } while (0)
    #define MFQ2(Xa, Xb, WS) do { \
        acc[0] = __builtin_amdgcn_mfma_f32_16x16x32_bf16(WS, Xa, acc[0], 0, 0, 0); \
        acc[1] = __builtin_amdgcn_mfma_f32_16x16x32_bf16(WS, Xb, acc[1], 0, 0, 0); } while (0)

    LW(WA, 0);  LW(WB, 1);  LW(WC, 2);

    #pragma unroll 1
    for (int qq = 0; qq < 9; ++qq) {
        const int T0 = qq*9;                 // global tap index of p0
        const int colq = m + qq;
        const char* xb = Xs + (size_t)((2*wr)*24 + colq)*64 + ((g ^ (colq & 3)) << 4);
        XA = *(const short8*)(xb);
        XB = *(const short8*)(xb + 1536);
        // taps p0..p8; ring slot = (T0+p)%3 stays phase-aligned (9%3==0)
        XC = *(const short8*)(xb + 2*1536);  MFQ2(XA, XB, WA); LW(WA, T0 + 3);   // p0
        XA = *(const short8*)(xb + 3*1536);  MFQ2(XB, XC, WB); LW(WB, T0 + 4);   // p1
        XB = *(const short8*)(xb + 4*1536);  MFQ2(XC, XA, WC); LW(WC, T0 + 5);   // p2
        XC = *(const short8*)(xb + 5*1536);  MFQ2(XA, XB, WA); LW(WA, T0 + 6);   // p3
        XA = *(const short8*)(xb + 6*1536);  MFQ2(XB, XC, WB); LW(WB, T0 + 7);   // p4
        XB = *(const short8*)(xb + 7*1536);  MFQ2(XC, XA, WC); LW(WC, T0 + 8);   // p5
        XC = *(const short8*)(xb + 8*1536);  MFQ2(XA, XB, WA); LW(WA, T0 + 9);   // p6
        XA = *(const short8*)(xb + 9*1536);  MFQ2(XB, XC, WB); LW(WB, T0 + 10);  // p7
                                             MFQ2(XC, XA, WC); LW(WC, T0 + 11);  // p8
    }
    #undef LW
    #undef MFQ2
    // (final column's W prefetches over-read 3 taps past this dir's region
    //  into adjacent d_ws buffers; values unused — harmless.)

    // ---- acc exchange through LDS: [hf][row 6][col 16] slots of 64B,
    //      co-group g stored at slot-offset ((g ^ (col&3))<<4). 12,288 B.
    __syncthreads();   // everyone done reading Xs
    {
        char* base = Xs + (size_t)(((hf*6 + 2*wr)*16) + m)*64 + ((g ^ (m & 3)) << 4);
        *(f32x4*)(base)        = acc[0];
        *(f32x4*)(base + 1024) = acc[1];   // +1 row = 16 slots * 64B
    }
    __syncthreads();

    // ---- vectorized complex epilogue: thread -> (row, co, 4-col quarter).
    //      Full float2 8B loads/stores, 32B contiguous per thread.
    const float am = (MODE >= 1) ? fabsf(miu[0]) : 0.f;
    float2 part = make_float2(0.f, 0.f);
    {
        const int row = t >> 6;            // 0..5
        const int co = (t >> 2) & 15;
        const int qt = t & 3;              // column quarter
        const int gs = co >> 2, js = co & 3;
        float re[4], im[4];
        #pragma unroll
        for (int k = 0; k < 4; ++k) {
            const int col = qt*4 + k;
            const int off = (row*16 + col)*64 + ((gs ^ (col & 3)) << 4) + js*4;
            re[k] = *(const float*)(Xs + off);
            im[k] = *(const float*)(Xs + off + 6144);
        }
        const int pixb = (i0 + row)*MM + j0 + qt*4;
        const size_t gidx = (size_t)co*NPIX + pixb;
        #pragma unroll
        for (int k = 0; k < 4; ++k) {
            if (MODE == 0) {
                const float2 tc = x[gidx + k];
                out[gidx + k] = make_float2(re[k] - tc.x, im[k] - tc.y);
            } else if (MODE == 1) {
                const float2 tc = x[gidx + k];
                const float2 pc = aux[gidx + k];
                const float mv = mask8[gidx + k] ? 1.f : 0.f;
                const float qr = re[k] - tc.x + (mv + am)*pc.x;
                const float qi = im[k] - tc.y + (mv + am)*pc.y;
                out[gidx + k] = make_float2(qr, qi);
                part.x += qr*pc.x + qi*pc.y;
                part.y += qi*pc.x - qr*pc.y;
            } else {
                const float2 tc = x[gidx + k];
                const float2 wc = aux[gidx + k];
                const float mv = mask8[gidx + k] ? 1.f : 0.f;
                const int pix = pixb + k;
                const float kcr = ks[(size_t)pix*32 + co];
                const float kci = ks[(size_t)pix*32 + co + 16];
                const float zr  = z[(size_t)pix*32 + co];
                const float zi  = z[(size_t)pix*32 + co + 16];
                const float pr = mv*kcr + am*zr - (re[k] - tc.x) - (mv + am)*wc.x;
                const float pi = mv*kci + am*zi - (im[k] - tc.y) - (mv + am)*wc.y;
                out[gidx + k]  = make_float2(pr, pi);
                out2[gidx + k] = make_float2(pr, pi);
                part.x += pr*pr + pi*pi;
            }
        }
    }
    if (MODE >= 1) {
        __syncthreads();
        part = block_reduce2(part);
        if (t == 0) partials[bi] = part;
    }
}

__global__ void finalize_rr(const float2* __restrict__ partials, float* __restrict__ scal, int n) {
    float2 s = make_float2(0.f, 0.f);
    for (int i = threadIdx.x; i < n; i += blockDim.x) { s.x += partials[i].x; s.y += partials[i].y; }
    s = block_reduce2(s);
    if (threadIdx.x == 0) scal[0] = s.x;
}

__global__ void finalize_alpha(const float2* __restrict__ partials, float* __restrict__ scal, int n) {
    float2 s = make_float2(0.f, 0.f);
    for (int i = threadIdx.x; i < n; i += blockDim.x) { s.x += partials[i].x; s.y += partials[i].y; }
    s = block_reduce2(s);
    if (threadIdx.x == 0) {
        const float rr = scal[0];
        const float d = s.x*s.x + s.y*s.y;
        scal[1] =  rr * s.x / d;
        scal[2] = -rr * s.y / d;
    }
}

// r -= alpha*q ; partial += |r|^2
__global__ void update_r(float2* __restrict__ r, const float2* __restrict__ q,
                         const float* __restrict__ scal, float2* __restrict__ partials) {
    const float ar = scal[1], ai = scal[2];
    float2 s = make_float2(0.f, 0.f);
    for (int e = blockIdx.x*256 + threadIdx.x; e < N2; e += NRED*256) {
        const float2 qv = q[e];
        float2 rv = r[e];
        rv.x -= ar*qv.x - ai*qv.y;
        rv.y -= ar*qv.y + ai*qv.x;
        r[e] = rv;
        s.x += rv.x*rv.x + rv.y*rv.y;
    }
    s = block_reduce2(s);
    if (threadIdx.x == 0) partials[blockIdx.x] = s;
}

__global__ void finalize_beta(const float2* __restrict__ partials, float* __restrict__ scal) {
    float2 v = partials[threadIdx.x];
    v = block_reduce2(v);
    if (threadIdx.x == 0) {
        const float rn = v.x;
        scal[3] = rn / scal[0];
        scal[0] = rn;
    }
}

// b += alpha*p_old ; p = r + beta*p_old
__global__ void update_pb(float2* __restrict__ p, const float2* __restrict__ r,
                          float2* __restrict__ b, const float* __restrict__ scal) {
    const float ar = scal[1], ai = scal[2], beta = scal[3];
    const int e = blockIdx.x*256 + threadIdx.x;
    if (e < N2) {
        const float2 pv = p[e], rv = r[e];
        float2 bv = b[e];
        bv.x += ar*pv.x - ai*pv.y;
        bv.y += ar*pv.y + ai*pv.x;
        b[e] = bv;
        p[e] = make_float2(rv.x + beta*pv.x, rv.y + beta*pv.y);
    }
}

// final iteration: only b += alpha*p is live
__global__ void update_bfinal(float2* __restrict__ b, const float2* __restrict__ p,
                              const float* __restrict__ scal) {
    const float ar = scal[1], ai = scal[2];
    const int e = blockIdx.x*256 + threadIdx.x;
    if (e < N2) {
        const float2 pv = p[e];
        float2 bv = b[e];
        bv.x += ar*pv.x - ai*pv.y;
        bv.y += ar*pv.y + ai*pv.x;
        b[e] = bv;
    }
}

__global__ void pack_out(const float2* __restrict__ b, float* __restrict__ out) {
    const int e = blockIdx.x*256 + threadIdx.x;
    if (e >= 32*NPIX) return;
    const int pix = e >> 5;
    const int cc  = e & 31;
    const float2 v = b[(size_t)(cc & 15)*NPIX + pix];
    out[e] = (cc < 16) ? v.x : v.y;
}

extern "C" void kernel_launch(void* const* d_in, const int* in_sizes, int n_in,
                              void* d_out, int out_size, void* d_ws, size_t ws_size,
                              hipStream_t stream) {
    const float* z    = (const float*)d_in[0];
    const float* ks   = (const float*)d_in[1];
    const float* kr   = (const float*)d_in[2];
    const float* ki   = (const float*)d_in[3];
    const float* prev = (const float*)d_in[5];
    const float* miu  = (const float*)d_in[6];
    float* out = (float*)d_out;

    char* w = (char*)d_ws;
    const size_t FB = (size_t)N2 * sizeof(float2);
    float2* wsf = (float2*)w; w += FB;    // b (in-place)
    float2* pf  = (float2*)w; w += FB;
    float2* rf  = (float2*)w; w += FB;
    float2* qf  = (float2*)w; w += FB;
    float2* tf  = (float2*)w; w += FB;
    u32* wbuf   = (u32*)w;   w += (size_t)2*162*256*sizeof(u32);   // 331776 B
    uint8_t* mask8 = (uint8_t*)w; w += (size_t)N2;
    w = (char*)(((uintptr_t)w + 255) & ~(uintptr_t)255);
    float2* partials = (float2*)w; w += (size_t)NCBLK * sizeof(float2);
    float*  scal     = (float*)w;

    const u32* wbF = wbuf;
    const u32* wbB = wbuf + (size_t)162*256;

    prep_weights<<<81, 256, 0, stream>>>(kr, ki, wbuf);
    prep_fields<<<576, 256, 0, stream>>>(ks, prev, wsf, mask8);

    conv9<0><<<NCBLK, 384, 0, stream>>>(wsf, wbF, tf, nullptr, nullptr, nullptr, nullptr, nullptr, nullptr, nullptr);
    conv9<2><<<NCBLK, 384, 0, stream>>>(tf, wbB, pf, rf, wsf, ks, z, mask8, miu, partials);
    finalize_rr<<<1, 256, 0, stream>>>(partials, scal, NCBLK);

    for (int it = 0; it < 10; ++it) {
        conv9<0><<<NCBLK, 384, 0, stream>>>(pf, wbF, tf, nullptr, nullptr, nullptr, nullptr, nullptr, nullptr, nullptr);
        conv9<1><<<NCBLK, 384, 0, stream>>>(tf, wbB, qf, nullptr, pf, nullptr, nullptr, mask8, miu, partials);
        finalize_alpha<<<1, 256, 0, stream>>>(partials, scal, NCBLK);
        if (it < 9) {
            update_r<<<NRED, 256, 0, stream>>>(rf, qf, scal, partials);
            finalize_beta<<<1, NRED, 0, stream>>>(partials, scal);
            update_pb<<<9216, 256, 0, stream>>>(pf, rf, wsf, scal);
        } else {
            update_bfinal<<<9216, 256, 0, stream>>>(wsf, pf, scal);
        }
    }

    pack_out<<<18432, 256, 0, stream>>>(wsf, out);
}

// Round 19
// 1100.835 us; speedup vs baseline: 1.0919x; 1.0919x over previous
//
#include <hip/hip_runtime.h>
#include <stdint.h>

// SPIRiT CG reconstruction. Convs: single-product bf16 MFMA (W and X RN bf16),
// per-tap implicit GEMM M=16 c_out, N=16 pixels, K=32 = 16 c_in x {re,im}.
// Conv kernel: 12x16 tile, 384 threads (6 waves = 2 components x 3 row-groups),
// grid 768 = 3 blocks/CU, XCD-swizzled. R19: corrected LDS slot swizzle
// SWZ(c) = (c>>1)&3 — the old (c&3) key shares its period-2 parity with the
// bank-set parity bit, mapping 4 lanes per bank-quad on every X ds_read_b128
// (4-way conflict, 2.5-4.2M conflict cycles/dispatch across R10-R18). The
// >>1 key gives 2 lanes/set (free). Same key used in staging writes, tap
// reads, acc exchange, epilogue — arithmetic identical to R13.

#define MM 384
#define NPIX (MM*MM)          // 147456
#define N2 (16*NPIX)
#define NRED 512
#define NCBLK 768             // 32 row-tiles (12 rows) x 24 col-tiles (16 cols)
#define SWZ(c) (((c) >> 1) & 3)

typedef __attribute__((ext_vector_type(8))) short short8;
typedef __attribute__((ext_vector_type(4))) float f32x4;
typedef unsigned int u32;

__device__ __forceinline__ float2 block_reduce2(float2 v) {
    #pragma unroll
    for (int off = 32; off > 0; off >>= 1) {
        v.x += __shfl_down(v.x, off);
        v.y += __shfl_down(v.y, off);
    }
    __shared__ float2 tmp[8];
    const int wid = threadIdx.x >> 6, lid = threadIdx.x & 63;
    if (lid == 0) tmp[wid] = v;
    __syncthreads();
    if (threadIdx.x == 0) {
        const int nw = blockDim.x >> 6;
        for (int i = 1; i < nw; ++i) { v.x += tmp[i].x; v.y += tmp[i].y; }
    }
    return v;
}

__device__ __forceinline__ u32 bf16rn(float f) {   // round-to-nearest-even bf16
    const u32 u = __float_as_uint(f);
    return (u + 0x7FFFu + ((u >> 16) & 1u)) >> 16;
}

// Weight fragments (RN bf16): [dir][slot=q*9+p][hf][lane64][4 u32]  (q-major)
// hf=0 rows: [Wr | -Wi] (-> real), hf=1 rows: [Wi | Wr] (-> imag);
// lane = co + 16*kgroup. Tap block = 2 KB (1 KB per hf).
__global__ void prep_weights(const float* __restrict__ kr, const float* __restrict__ ki,
                             u32* __restrict__ wbuf) {
    const int e = blockIdx.x * 256 + threadIdx.x;
    if (e >= 20736) return;    // 2 dir x 81 tap x 2 hf x 64 lane
    const int lane = e & 63;
    int r = e >> 6;
    const int hf = r & 1; r >>= 1;
    const int q = r % 9; r /= 9;
    const int p = r % 9; r /= 9;
    const int dir = r;
    const int co = lane & 15, g = lane >> 4;
    float vv[8];
    #pragma unroll
    for (int t = 0; t < 8; ++t) {
        const int kc = 8 * g + t;
        const int ci = kc & 15;
        const int isI = kc >> 4;
        int sidx;
        if (dir == 0) sidx = (q*9 + p)*256 + ci*16 + co;          // Wf[co,ci,p,q]=K[q,p,ci,co]
        else          sidx = ((8-q)*9 + (8-p))*256 + co*16 + ci;  // Wb = conj flip swap
        const float wr = kr[sidx];
        const float wi = (dir == 0) ? ki[sidx] : -ki[sidx];
        vv[t] = (hf == 0) ? (isI ? -wi : wr) : (isI ? wr : wi);
    }
    u32 pk[4];
    #pragma unroll
    for (int t = 0; t < 4; ++t) pk[t] = bf16rn(vv[2*t]) | (bf16rn(vv[2*t+1]) << 16);
    u32* o = wbuf + (size_t)(dir*162 + (q*9 + p)*2 + hf)*256 + lane*4;
    *(uint4*)o = make_uint4(pk[0], pk[1], pk[2], pk[3]);
}

__global__ void prep_fields(const float* __restrict__ ks, const float* __restrict__ prev,
                            float2* __restrict__ wsf, uint8_t* __restrict__ mask8) {
    const int pix = blockIdx.x * blockDim.x + threadIdx.x;
    if (pix >= NPIX) return;
    #pragma unroll
    for (int c = 0; c < 16; ++c) {
        const float krr = ks[(size_t)pix*32 + c];
        const float kii = ks[(size_t)pix*32 + c + 16];
        mask8[(size_t)c*NPIX + pix] = (krr != 0.f || kii != 0.f) ? 1 : 0;
        wsf[(size_t)c*NPIX + pix] = make_float2(prev[(size_t)pix*32 + c], prev[(size_t)pix*32 + c + 16]);
    }
}

// MODE 0: out = conv(x) - x
// MODE 1: out = conv(x) - x + (mask+am)*aux ; partial += out*conj(aux)
// MODE 2: out=out2 = mask*kk + am*z - (conv(x)-x) - (mask+am)*aux ; partial += |out|^2
template<int MODE>
__global__ __launch_bounds__(384, 5)
void conv9(const float2* __restrict__ x, const u32* __restrict__ Wd,
           float2* __restrict__ out, float2* __restrict__ out2,
           const float2* __restrict__ aux, const float* __restrict__ ks,
           const float* __restrict__ z, const uint8_t* __restrict__ mask8,
           const float* __restrict__ miu, float2* __restrict__ partials)
{
    __shared__ __align__(16) char Xs[20*24*64];   // 30720 B; reused for acc exchange
    const int t = threadIdx.x;
    const int bi0 = blockIdx.x;
    const int bi = (bi0 & 7) * 96 + (bi0 >> 3);   // XCD swizzle: 4-tile-row band/XCD
    const int i0 = (bi / 24) * 12;
    const int j0 = (bi % 24) * 16;
    const int w = t >> 6, lane = t & 63;
    const int hf = (w >= 3) ? 1 : 0;  // 0: real component, 1: imag component
    const int wr = w - 3*hf;          // row group (rows 4wr..4wr+3)
    const int m = lane & 15, g = lane >> 4;

    // ---- stage 20x24 slab (rows i0-4..i0+15, cols j0-4..j0+19), bf16 RN,
    //      64 B/px: 4 slots of 16B, content c stored at slot c ^ SWZ(col).
    for (int u = t; u < 20*24; u += 384) {
        const int col = u % 24, row = u / 24;
        const int row_g = i0 - 4 + row, col_g = j0 - 4 + col;
        const bool valid = ((unsigned)row_g < MM) && ((unsigned)col_g < MM);
        const float2* src = x + (size_t)row_g*MM + col_g;
        float2 v[16];
        #pragma unroll
        for (int ci = 0; ci < 16; ++ci)
            v[ci] = valid ? src[(size_t)ci*NPIX] : make_float2(0.f, 0.f);
        u32 c0[4], c1[4], c2[4], c3[4];
        #pragma unroll
        for (int j = 0; j < 4; ++j) {
            c0[j] = bf16rn(v[2*j].x)     | (bf16rn(v[2*j+1].x) << 16);
            c1[j] = bf16rn(v[8+2*j].x)   | (bf16rn(v[9+2*j].x) << 16);
            c2[j] = bf16rn(v[2*j].y)     | (bf16rn(v[2*j+1].y) << 16);
            c3[j] = bf16rn(v[8+2*j].y)   | (bf16rn(v[9+2*j].y) << 16);
        }
        const int k3 = SWZ(col);
        char* pb = Xs + (size_t)(row*24 + col)*64;
        *(uint4*)(pb + (((0 ^ k3)) << 4)) = make_uint4(c0[0], c0[1], c0[2], c0[3]);
        *(uint4*)(pb + (((1 ^ k3)) << 4)) = make_uint4(c1[0], c1[1], c1[2], c1[3]);
        *(uint4*)(pb + (((2 ^ k3)) << 4)) = make_uint4(c2[0], c2[1], c2[2], c2[3]);
        *(uint4*)(pb + (((3 ^ k3)) << 4)) = make_uint4(c3[0], c3[1], c3[2], c3[3]);
    }
    __syncthreads();

    f32x4 acc[4];
    #pragma unroll
    for (int a = 0; a < 4; ++a) acc[a] = (f32x4){0.f, 0.f, 0.f, 0.f};

    // ---- 81 taps, q-outer / p-inner (unrolled 9). X ring-6, W ring-9,
    //      compute-then-prefetch (R8 bug: reversed order clobbers the ring).
    const char* wl = (const char*)Wd + (lane << 4) + (hf << 10);
    short8 W0, W1, W2, W3, W4, W5, W6, W7, W8;
    short8 X0, X1, X2, X3, X4, X5;

    #define LW(WS, ADDR) do { WS = *(const short8*)(ADDR); } while (0)
    #define MFQ(Xa, Xb, Xc, Xd, WS) do { \
        acc[0] = __builtin_amdgcn_mfma_f32_16x16x32_bf16(WS, Xa, acc[0], 0, 0, 0); \
        acc[1] = __builtin_amdgcn_mfma_f32_16x16x32_bf16(WS, Xb, acc[1], 0, 0, 0); \
        acc[2] = __builtin_amdgcn_mfma_f32_16x16x32_bf16(WS, Xc, acc[2], 0, 0, 0); \
        acc[3] = __builtin_amdgcn_mfma_f32_16x16x32_bf16(WS, Xd, acc[3], 0, 0, 0); } while (0)

    LW(W0, wl);            LW(W1, wl + 2048);   LW(W2, wl + 4096);
    LW(W3, wl + 6144);     LW(W4, wl + 8192);   LW(W5, wl + 10240);
    LW(W6, wl + 12288);    LW(W7, wl + 14336);  LW(W8, wl + 16384);
    {
        const char* xb0 = Xs + (size_t)((4*wr)*24 + m)*64 + ((g ^ SWZ(m)) << 4);
        X0 = *(const short8*)(xb0);
        X1 = *(const short8*)(xb0 + 1536);
        X2 = *(const short8*)(xb0 + 2*1536);
        X3 = *(const short8*)(xb0 + 3*1536);
        X4 = *(const short8*)(xb0 + 4*1536);
    }

    #pragma unroll 1
    for (int qq = 0; qq < 9; ++qq) {
        const char* wq = wl + (size_t)qq * 18432 + 18432;   // next column taps
        const int colq = m + qq;
        const char* xb  = Xs + (size_t)((4*wr)*24 + colq)*64 + ((g ^ SWZ(colq)) << 4);
        const int colq1 = colq + 1;
        const char* xbn = Xs + (size_t)((4*wr)*24 + colq1)*64 + ((g ^ SWZ(colq1)) << 4);

        MFQ(X0, X1, X2, X3, W0); LW(W0, wq);           X5 = *(const short8*)(xb + 5*1536);   // p0
        MFQ(X1, X2, X3, X4, W1); LW(W1, wq + 2048);    X0 = *(const short8*)(xb + 6*1536);   // p1
        MFQ(X2, X3, X4, X5, W2); LW(W2, wq + 4096);    X1 = *(const short8*)(xb + 7*1536);   // p2
        MFQ(X3, X4, X5, X0, W3); LW(W3, wq + 6144);    X2 = *(const short8*)(xb + 8*1536);   // p3
        MFQ(X4, X5, X0, X1, W4); LW(W4, wq + 8192);    X3 = *(const short8*)(xb + 9*1536);   // p4
        MFQ(X5, X0, X1, X2, W5); LW(W5, wq + 10240);   X4 = *(const short8*)(xb + 10*1536);  // p5
        MFQ(X0, X1, X2, X3, W6); LW(W6, wq + 12288);   X5 = *(const short8*)(xb + 11*1536);  // p6
        MFQ(X1, X2, X3, X4, W7); LW(W7, wq + 14336);   X0 = *(const short8*)(xbn);           // p7
        MFQ(X2, X3, X4, X5, W8); LW(W8, wq + 16384);   X1 = *(const short8*)(xbn + 1536);    // p8
        X2 = *(const short8*)(xbn + 2*1536);
        X3 = *(const short8*)(xbn + 3*1536);
        X4 = *(const short8*)(xbn + 4*1536);
    }
    #undef LW
    #undef MFQ
    // (last column's W prefetches over-read ~18 KB past this dir's W region
    //  into the mask8 workspace buffer; values unused — harmless.)

    // ---- acc exchange through LDS: [hf][row 12][col 16] slots of 64B,
    //      co-group g stored at slot-offset ((g ^ SWZ(col))<<4). 24,576 B.
    __syncthreads();   // everyone done reading Xs
    {
        char* base = Xs + (size_t)(((hf*12 + 4*wr)*16) + m)*64 + ((g ^ SWZ(m)) << 4);
        *(f32x4*)(base)        = acc[0];
        *(f32x4*)(base + 1024) = acc[1];   // +1 row = 16 slots * 64B
        *(f32x4*)(base + 2048) = acc[2];
        *(f32x4*)(base + 3072) = acc[3];
    }
    __syncthreads();

    // ---- vectorized complex epilogue: thread -> (co, row, 8-col half).
    //      Full float2 8B loads/stores, 64B contiguous per thread.
    const float am = (MODE >= 1) ? fabsf(miu[0]) : 0.f;
    float2 part = make_float2(0.f, 0.f);
    {
        const int pair = t >> 1, ch = t & 1;
        const int co = pair & 15, row = pair >> 4;       // row 0..11
        const int gs = co >> 2, js = co & 3;
        float re[8], im[8];
        #pragma unroll
        for (int k = 0; k < 8; ++k) {
            const int col = ch*8 + k;
            const int off = (row*16 + col)*64 + ((gs ^ SWZ(col)) << 4) + js*4;
            re[k] = *(const float*)(Xs + off);
            im[k] = *(const float*)(Xs + off + 12288);
        }
        const int pixb = (i0 + row)*MM + j0 + ch*8;
        const size_t gidx = (size_t)co*NPIX + pixb;
        #pragma unroll
        for (int k = 0; k < 8; ++k) {
            if (MODE == 0) {
                const float2 tc = x[gidx + k];
                out[gidx + k] = make_float2(re[k] - tc.x, im[k] - tc.y);
            } else if (MODE == 1) {
                const float2 tc = x[gidx + k];
                const float2 pc = aux[gidx + k];
                const float mv = mask8[gidx + k] ? 1.f : 0.f;
                const float qr = re[k] - tc.x + (mv + am)*pc.x;
                const float qi = im[k] - tc.y + (mv + am)*pc.y;
                out[gidx + k] = make_float2(qr, qi);
                part.x += qr*pc.x + qi*pc.y;
                part.y += qi*pc.x - qr*pc.y;
            } else {
                const float2 tc = x[gidx + k];
                const float2 wc = aux[gidx + k];
                const float mv = mask8[gidx + k] ? 1.f : 0.f;
                const int pix = pixb + k;
                const float kcr = ks[(size_t)pix*32 + co];
                const float kci = ks[(size_t)pix*32 + co + 16];
                const float zr  = z[(size_t)pix*32 + co];
                const float zi  = z[(size_t)pix*32 + co + 16];
                const float pr = mv*kcr + am*zr - (re[k] - tc.x) - (mv + am)*wc.x;
                const float pi = mv*kci + am*zi - (im[k] - tc.y) - (mv + am)*wc.y;
                out[gidx + k]  = make_float2(pr, pi);
                out2[gidx + k] = make_float2(pr, pi);
                part.x += pr*pr + pi*pi;
            }
        }
    }
    if (MODE >= 1) {
        __syncthreads();
        part = block_reduce2(part);
        if (t == 0) partials[bi] = part;
    }
}

__global__ void finalize_rr(const float2* __restrict__ partials, float* __restrict__ scal, int n) {
    float2 s = make_float2(0.f, 0.f);
    for (int i = threadIdx.x; i < n; i += blockDim.x) { s.x += partials[i].x; s.y += partials[i].y; }
    s = block_reduce2(s);
    if (threadIdx.x == 0) scal[0] = s.x;
}

__global__ void finalize_alpha(const float2* __restrict__ partials, float* __restrict__ scal, int n) {
    float2 s = make_float2(0.f, 0.f);
    for (int i = threadIdx.x; i < n; i += blockDim.x) { s.x += partials[i].x; s.y += partials[i].y; }
    s = block_reduce2(s);
    if (threadIdx.x == 0) {
        const float rr = scal[0];
        const float d = s.x*s.x + s.y*s.y;
        scal[1] =  rr * s.x / d;
        scal[2] = -rr * s.y / d;
    }
}

// r -= alpha*q ; partial += |r|^2
__global__ void update_r(float2* __restrict__ r, const float2* __restrict__ q,
                         const float* __restrict__ scal, float2* __restrict__ partials) {
    const float ar = scal[1], ai = scal[2];
    float2 s = make_float2(0.f, 0.f);
    for (int e = blockIdx.x*256 + threadIdx.x; e < N2; e += NRED*256) {
        const float2 qv = q[e];
        float2 rv = r[e];
        rv.x -= ar*qv.x - ai*qv.y;
        rv.y -= ar*qv.y + ai*qv.x;
        r[e] = rv;
        s.x += rv.x*rv.x + rv.y*rv.y;
    }
    s = block_reduce2(s);
    if (threadIdx.x == 0) partials[blockIdx.x] = s;
}

__global__ void finalize_beta(const float2* __restrict__ partials, float* __restrict__ scal) {
    float2 v = partials[threadIdx.x];
    v = block_reduce2(v);
    if (threadIdx.x == 0) {
        const float rn = v.x;
        scal[3] = rn / scal[0];
        scal[0] = rn;
    }
}

// b += alpha*p_old ; p = r + beta*p_old
__global__ void update_pb(float2* __restrict__ p, const float2* __restrict__ r,
                          float2* __restrict__ b, const float* __restrict__ scal) {
    const float ar = scal[1], ai = scal[2], beta = scal[3];
    const int e = blockIdx.x*256 + threadIdx.x;
    if (e < N2) {
        const float2 pv = p[e], rv = r[e];
        float2 bv = b[e];
        bv.x += ar*pv.x - ai*pv.y;
        bv.y += ar*pv.y + ai*pv.x;
        b[e] = bv;
        p[e] = make_float2(rv.x + beta*pv.x, rv.y + beta*pv.y);
    }
}

// final iteration: only b += alpha*p is live
__global__ void update_bfinal(float2* __restrict__ b, const float2* __restrict__ p,
                              const float* __restrict__ scal) {
    const float ar = scal[1], ai = scal[2];
    const int e = blockIdx.x*256 + threadIdx.x;
    if (e < N2) {
        const float2 pv = p[e];
        float2 bv = b[e];
        bv.x += ar*pv.x - ai*pv.y;
        bv.y += ar*pv.y + ai*pv.x;
        b[e] = bv;
    }
}

__global__ void pack_out(const float2* __restrict__ b, float* __restrict__ out) {
    const int e = blockIdx.x*256 + threadIdx.x;
    if (e >= 32*NPIX) return;
    const int pix = e >> 5;
    const int cc  = e & 31;
    const float2 v = b[(size_t)(cc & 15)*NPIX + pix];
    out[e] = (cc < 16) ? v.x : v.y;
}

extern "C" void kernel_launch(void* const* d_in, const int* in_sizes, int n_in,
                              void* d_out, int out_size, void* d_ws, size_t ws_size,
                              hipStream_t stream) {
    const float* z    = (const float*)d_in[0];
    const float* ks   = (const float*)d_in[1];
    const float* kr   = (const float*)d_in[2];
    const float* ki   = (const float*)d_in[3];
    const float* prev = (const float*)d_in[5];
    const float* miu  = (const float*)d_in[6];
    float* out = (float*)d_out;

    char* w = (char*)d_ws;
    const size_t FB = (size_t)N2 * sizeof(float2);
    float2* wsf = (float2*)w; w += FB;    // b (in-place)
    float2* pf  = (float2*)w; w += FB;
    float2* rf  = (float2*)w; w += FB;
    float2* qf  = (float2*)w; w += FB;
    float2* tf  = (float2*)w; w += FB;
    u32* wbuf   = (u32*)w;   w += (size_t)2*162*256*sizeof(u32);   // 331776 B
    uint8_t* mask8 = (uint8_t*)w; w += (size_t)N2;
    w = (char*)(((uintptr_t)w + 255) & ~(uintptr_t)255);
    float2* partials = (float2*)w; w += (size_t)NCBLK * sizeof(float2);
    float*  scal     = (float*)w;

    const u32* wbF = wbuf;
    const u32* wbB = wbuf + (size_t)162*256;

    prep_weights<<<81, 256, 0, stream>>>(kr, ki, wbuf);
    prep_fields<<<576, 256, 0, stream>>>(ks, prev, wsf, mask8);

    conv9<0><<<NCBLK, 384, 0, stream>>>(wsf, wbF, tf, nullptr, nullptr, nullptr, nullptr, nullptr, nullptr, nullptr);
    conv9<2><<<NCBLK, 384, 0, stream>>>(tf, wbB, pf, rf, wsf, ks, z, mask8, miu, partials);
    finalize_rr<<<1, 256, 0, stream>>>(partials, scal, NCBLK);

    for (int it = 0; it < 10; ++it) {
        conv9<0><<<NCBLK, 384, 0, stream>>>(pf, wbF, tf, nullptr, nullptr, nullptr, nullptr, nullptr, nullptr, nullptr);
        conv9<1><<<NCBLK, 384, 0, stream>>>(tf, wbB, qf, nullptr, pf, nullptr, nullptr, mask8, miu, partials);
        finalize_alpha<<<1, 256, 0, stream>>>(partials, scal, NCBLK);
        if (it < 9) {
            update_r<<<NRED, 256, 0, stream>>>(rf, qf, scal, partials);
            finalize_beta<<<1, NRED, 0, stream>>>(partials, scal);
            update_pb<<<9216, 256, 0, stream>>>(pf, rf, wsf, scal);
        } else {
            update_bfinal<<<9216, 256, 0, stream>>>(wsf, pf, scal);
        }
    }

    pack_out<<<18432, 256, 0, stream>>>(wsf, out);
}

// Round 20
// 1020.593 us; speedup vs baseline: 1.1777x; 1.0786x over previous
//
#include <hip/hip_runtime.h>
#include <stdint.h>

// SPIRiT CG reconstruction. Convs: single-product bf16 MFMA (W and X RN bf16),
// per-tap implicit GEMM M=16 c_out, N=16 pixels, K=32 = 16 c_in x {re,im}.
// R20 = R12 (best measured total, 1022us) + conflict-free LDS slot key
// SWZ(c)=(c>>1)&3 (R19-verified: 2.47M -> 147K conflict cycles) + fused
// final b-update+pack kernel. Conv: 12x16 tile, 384 threads (6 waves =
// 2 components x 3 row-groups), grid 768 = 3 blocks/CU, XCD-swizzled,
// X ring-6 + W ring-9, compute-then-prefetch, scalar hf-split epilogue.

#define MM 384
#define NPIX (MM*MM)          // 147456
#define N2 (16*NPIX)
#define NRED 512
#define NCBLK 768             // 32 row-tiles (12 rows) x 24 col-tiles (16 cols)
#define SWZ(c) (((c) >> 1) & 3)

typedef __attribute__((ext_vector_type(8))) short short8;
typedef __attribute__((ext_vector_type(4))) float f32x4;
typedef unsigned int u32;

__device__ __forceinline__ float2 block_reduce2(float2 v) {
    #pragma unroll
    for (int off = 32; off > 0; off >>= 1) {
        v.x += __shfl_down(v.x, off);
        v.y += __shfl_down(v.y, off);
    }
    __shared__ float2 tmp[8];
    const int wid = threadIdx.x >> 6, lid = threadIdx.x & 63;
    if (lid == 0) tmp[wid] = v;
    __syncthreads();
    if (threadIdx.x == 0) {
        const int nw = blockDim.x >> 6;
        for (int i = 1; i < nw; ++i) { v.x += tmp[i].x; v.y += tmp[i].y; }
    }
    return v;
}

__device__ __forceinline__ u32 bf16rn(float f) {   // round-to-nearest-even bf16
    const u32 u = __float_as_uint(f);
    return (u + 0x7FFFu + ((u >> 16) & 1u)) >> 16;
}

// Weight fragments (RN bf16): [dir][slot=q*9+p][hf][lane64][4 u32]  (q-major)
// hf=0 rows: [Wr | -Wi] (-> real), hf=1 rows: [Wi | Wr] (-> imag);
// lane = co + 16*kgroup. Tap block = 2 KB (1 KB per hf).
__global__ void prep_weights(const float* __restrict__ kr, const float* __restrict__ ki,
                             u32* __restrict__ wbuf) {
    const int e = blockIdx.x * 256 + threadIdx.x;
    if (e >= 20736) return;    // 2 dir x 81 tap x 2 hf x 64 lane
    const int lane = e & 63;
    int r = e >> 6;
    const int hf = r & 1; r >>= 1;
    const int q = r % 9; r /= 9;
    const int p = r % 9; r /= 9;
    const int dir = r;
    const int co = lane & 15, g = lane >> 4;
    float vv[8];
    #pragma unroll
    for (int t = 0; t < 8; ++t) {
        const int kc = 8 * g + t;
        const int ci = kc & 15;
        const int isI = kc >> 4;
        int sidx;
        if (dir == 0) sidx = (q*9 + p)*256 + ci*16 + co;          // Wf[co,ci,p,q]=K[q,p,ci,co]
        else          sidx = ((8-q)*9 + (8-p))*256 + co*16 + ci;  // Wb = conj flip swap
        const float wr = kr[sidx];
        const float wi = (dir == 0) ? ki[sidx] : -ki[sidx];
        vv[t] = (hf == 0) ? (isI ? -wi : wr) : (isI ? wr : wi);
    }
    u32 pk[4];
    #pragma unroll
    for (int t = 0; t < 4; ++t) pk[t] = bf16rn(vv[2*t]) | (bf16rn(vv[2*t+1]) << 16);
    u32* o = wbuf + (size_t)(dir*162 + (q*9 + p)*2 + hf)*256 + lane*4;
    *(uint4*)o = make_uint4(pk[0], pk[1], pk[2], pk[3]);
}

__global__ void prep_fields(const float* __restrict__ ks, const float* __restrict__ prev,
                            float2* __restrict__ wsf, uint8_t* __restrict__ mask8) {
    const int pix = blockIdx.x * blockDim.x + threadIdx.x;
    if (pix >= NPIX) return;
    #pragma unroll
    for (int c = 0; c < 16; ++c) {
        const float krr = ks[(size_t)pix*32 + c];
        const float kii = ks[(size_t)pix*32 + c + 16];
        mask8[(size_t)c*NPIX + pix] = (krr != 0.f || kii != 0.f) ? 1 : 0;
        wsf[(size_t)c*NPIX + pix] = make_float2(prev[(size_t)pix*32 + c], prev[(size_t)pix*32 + c + 16]);
    }
}

// MODE 0: out = conv(x) - x
// MODE 1: out = conv(x) - x + (mask+am)*aux ; partial += out*conj(aux)
// MODE 2: out=out2 = mask*kk + am*z - (conv(x)-x) - (mask+am)*aux ; partial += |out|^2
// Each wave handles ONE component (hf); all epilogue math is separable.
template<int MODE>
__global__ __launch_bounds__(384, 5)
void conv9(const float2* __restrict__ x, const u32* __restrict__ Wd,
           float2* __restrict__ out, float2* __restrict__ out2,
           const float2* __restrict__ aux, const float* __restrict__ ks,
           const float* __restrict__ z, const uint8_t* __restrict__ mask8,
           const float* __restrict__ miu, float2* __restrict__ partials)
{
    __shared__ __align__(16) char Xs[20*24*64];   // 30720 B
    const int t = threadIdx.x;
    const int bi0 = blockIdx.x;
    const int bi = (bi0 & 7) * 96 + (bi0 >> 3);   // XCD swizzle: 4-tile-row band/XCD
    const int i0 = (bi / 24) * 12;
    const int j0 = (bi % 24) * 16;
    const int w = t >> 6, lane = t & 63;
    const int hf = (w >= 3) ? 1 : 0;  // 0: real component, 1: imag component
    const int wr = w - 3*hf;          // row group (rows 4wr..4wr+3)
    const int m = lane & 15, g = lane >> 4;

    // ---- stage 20x24 slab (rows i0-4..i0+15, cols j0-4..j0+19), bf16 RN,
    //      64 B/px: 4 slots of 16B, content c stored at slot c ^ SWZ(col).
    for (int u = t; u < 20*24; u += 384) {
        const int col = u % 24, row = u / 24;
        const int row_g = i0 - 4 + row, col_g = j0 - 4 + col;
        const bool valid = ((unsigned)row_g < MM) && ((unsigned)col_g < MM);
        const float2* src = x + (size_t)row_g*MM + col_g;
        float2 v[16];
        #pragma unroll
        for (int ci = 0; ci < 16; ++ci)
            v[ci] = valid ? src[(size_t)ci*NPIX] : make_float2(0.f, 0.f);
        u32 c0[4], c1[4], c2[4], c3[4];
        #pragma unroll
        for (int j = 0; j < 4; ++j) {
            c0[j] = bf16rn(v[2*j].x)     | (bf16rn(v[2*j+1].x) << 16);
            c1[j] = bf16rn(v[8+2*j].x)   | (bf16rn(v[9+2*j].x) << 16);
            c2[j] = bf16rn(v[2*j].y)     | (bf16rn(v[2*j+1].y) << 16);
            c3[j] = bf16rn(v[8+2*j].y)   | (bf16rn(v[9+2*j].y) << 16);
        }
        const int k3 = SWZ(col);
        char* pb = Xs + (size_t)(row*24 + col)*64;
        *(uint4*)(pb + (((0 ^ k3)) << 4)) = make_uint4(c0[0], c0[1], c0[2], c0[3]);
        *(uint4*)(pb + (((1 ^ k3)) << 4)) = make_uint4(c1[0], c1[1], c1[2], c1[3]);
        *(uint4*)(pb + (((2 ^ k3)) << 4)) = make_uint4(c2[0], c2[1], c2[2], c2[3]);
        *(uint4*)(pb + (((3 ^ k3)) << 4)) = make_uint4(c3[0], c3[1], c3[2], c3[3]);
    }
    __syncthreads();

    f32x4 acc[4];
    #pragma unroll
    for (int a = 0; a < 4; ++a) acc[a] = (f32x4){0.f, 0.f, 0.f, 0.f};

    // ---- 81 taps, q-outer / p-inner (unrolled 9). X ring-6 (>=2-tap distance,
    //      cross-column tail loads), W ring-9 (next-column prefetch), compute-
    //      then-prefetch ordering (R8 bug: reversed order clobbers the ring).
    const char* wl = (const char*)Wd + (lane << 4) + (hf << 10);
    short8 W0, W1, W2, W3, W4, W5, W6, W7, W8;
    short8 X0, X1, X2, X3, X4, X5;

    #define LW(WS, ADDR) do { WS = *(const short8*)(ADDR); } while (0)
    #define MFQ(Xa, Xb, Xc, Xd, WS) do { \
        acc[0] = __builtin_amdgcn_mfma_f32_16x16x32_bf16(WS, Xa, acc[0], 0, 0, 0); \
        acc[1] = __builtin_amdgcn_mfma_f32_16x16x32_bf16(WS, Xb, acc[1], 0, 0, 0); \
        acc[2] = __builtin_amdgcn_mfma_f32_16x16x32_bf16(WS, Xc, acc[2], 0, 0, 0); \
        acc[3] = __builtin_amdgcn_mfma_f32_16x16x32_bf16(WS, Xd, acc[3], 0, 0, 0); } while (0)

    LW(W0, wl);            LW(W1, wl + 2048);   LW(W2, wl + 4096);
    LW(W3, wl + 6144);     LW(W4, wl + 8192);   LW(W5, wl + 10240);
    LW(W6, wl + 12288);    LW(W7, wl + 14336);  LW(W8, wl + 16384);
    {
        const char* xb0 = Xs + (size_t)((4*wr)*24 + m)*64 + ((g ^ SWZ(m)) << 4);
        X0 = *(const short8*)(xb0);
        X1 = *(const short8*)(xb0 + 1536);
        X2 = *(const short8*)(xb0 + 2*1536);
        X3 = *(const short8*)(xb0 + 3*1536);
        X4 = *(const short8*)(xb0 + 4*1536);
    }

    #pragma unroll 1
    for (int qq = 0; qq < 9; ++qq) {
        const char* wq = wl + (size_t)qq * 18432 + 18432;   // next column taps
        const int colq = m + qq;
        const char* xb  = Xs + (size_t)((4*wr)*24 + colq)*64 + ((g ^ SWZ(colq)) << 4);
        const int colq1 = colq + 1;
        const char* xbn = Xs + (size_t)((4*wr)*24 + colq1)*64 + ((g ^ SWZ(colq1)) << 4);

        MFQ(X0, X1, X2, X3, W0); LW(W0, wq);           X5 = *(const short8*)(xb + 5*1536);   // p0
        MFQ(X1, X2, X3, X4, W1); LW(W1, wq + 2048);    X0 = *(const short8*)(xb + 6*1536);   // p1
        MFQ(X2, X3, X4, X5, W2); LW(W2, wq + 4096);    X1 = *(const short8*)(xb + 7*1536);   // p2
        MFQ(X3, X4, X5, X0, W3); LW(W3, wq + 6144);    X2 = *(const short8*)(xb + 8*1536);   // p3
        MFQ(X4, X5, X0, X1, W4); LW(W4, wq + 8192);    X3 = *(const short8*)(xb + 9*1536);   // p4
        MFQ(X5, X0, X1, X2, W5); LW(W5, wq + 10240);   X4 = *(const short8*)(xb + 10*1536);  // p5
        MFQ(X0, X1, X2, X3, W6); LW(W6, wq + 12288);   X5 = *(const short8*)(xb + 11*1536);  // p6
        MFQ(X1, X2, X3, X4, W7); LW(W7, wq + 14336);   X0 = *(const short8*)(xbn);           // p7
        MFQ(X2, X3, X4, X5, W8); LW(W8, wq + 16384);   X1 = *(const short8*)(xbn + 1536);    // p8
        X2 = *(const short8*)(xbn + 2*1536);
        X3 = *(const short8*)(xbn + 3*1536);
        X4 = *(const short8*)(xbn + 4*1536);
    }
    #undef LW
    #undef MFQ
    // (last column's W prefetches over-read ~18 KB past this dir's W region
    //  into the mask8 workspace buffer; values unused — harmless.)

    // ---- epilogue: C/D col = lane&15 = pixel col, row = g*4+j = co.
    //      This wave stores only component hf of each float2; cross-component
    //      dot terms are separable and summed in the block reduction.
    const float am = (MODE >= 1) ? fabsf(miu[0]) : 0.f;
    float2 part = make_float2(0.f, 0.f);
    const float* xf  = (const float*)x;
    const float* axf = (const float*)aux;
    float* of  = (float*)out;
    float* o2f = (float*)out2;
    #pragma unroll
    for (int r = 0; r < 4; ++r) {
        const int rowo = i0 + 4*wr + r;
        const int colo = j0 + m;
        const int pix = rowo*MM + colo;
        #pragma unroll
        for (int j = 0; j < 4; ++j) {
            const int co = g*4 + j;
            const size_t idx = (size_t)co*NPIX + pix;
            const float v = acc[r][j];
            if (MODE == 0) {
                of[2*idx + hf] = v - xf[2*idx + hf];
            } else if (MODE == 1) {
                const float tc = xf[2*idx + hf];
                const float2 pc = aux[idx];
                const float pc_c = hf ? pc.y : pc.x;
                const float mv = mask8[idx] ? 1.f : 0.f;
                const float qc = v - tc + (mv + am)*pc_c;
                of[2*idx + hf] = qc;
                // part = sum q*conj(p): re += qr*pr + qi*pi ; im += qi*pr - qr*pi
                part.x += qc * pc_c;
                part.y += hf ? qc * pc.x : -qc * pc.y;
            } else {
                const float tc = xf[2*idx + hf];
                const float wc = axf[2*idx + hf];
                const float mv = mask8[idx] ? 1.f : 0.f;
                const float kc = ks[(size_t)pix*32 + co + 16*hf];
                const float zc = z[(size_t)pix*32 + co + 16*hf];
                const float pc = mv*kc + am*zc - (v - tc) - (mv + am)*wc;
                of[2*idx + hf]  = pc;
                o2f[2*idx + hf] = pc;
                part.x += pc * pc;
            }
        }
    }
    if (MODE >= 1) {
        __syncthreads();
        part = block_reduce2(part);
        if (t == 0) partials[bi] = part;
    }
}

__global__ void finalize_rr(const float2* __restrict__ partials, float* __restrict__ scal, int n) {
    float2 s = make_float2(0.f, 0.f);
    for (int i = threadIdx.x; i < n; i += blockDim.x) { s.x += partials[i].x; s.y += partials[i].y; }
    s = block_reduce2(s);
    if (threadIdx.x == 0) scal[0] = s.x;
}

__global__ void finalize_alpha(const float2* __restrict__ partials, float* __restrict__ scal, int n) {
    float2 s = make_float2(0.f, 0.f);
    for (int i = threadIdx.x; i < n; i += blockDim.x) { s.x += partials[i].x; s.y += partials[i].y; }
    s = block_reduce2(s);
    if (threadIdx.x == 0) {
        const float rr = scal[0];
        const float d = s.x*s.x + s.y*s.y;
        scal[1] =  rr * s.x / d;
        scal[2] = -rr * s.y / d;
    }
}

// r -= alpha*q ; partial += |r|^2
__global__ void update_r(float2* __restrict__ r, const float2* __restrict__ q,
                         const float* __restrict__ scal, float2* __restrict__ partials) {
    const float ar = scal[1], ai = scal[2];
    float2 s = make_float2(0.f, 0.f);
    for (int e = blockIdx.x*256 + threadIdx.x; e < N2; e += NRED*256) {
        const float2 qv = q[e];
        float2 rv = r[e];
        rv.x -= ar*qv.x - ai*qv.y;
        rv.y -= ar*qv.y + ai*qv.x;
        r[e] = rv;
        s.x += rv.x*rv.x + rv.y*rv.y;
    }
    s = block_reduce2(s);
    if (threadIdx.x == 0) partials[blockIdx.x] = s;
}

__global__ void finalize_beta(const float2* __restrict__ partials, float* __restrict__ scal) {
    float2 v = partials[threadIdx.x];
    v = block_reduce2(v);
    if (threadIdx.x == 0) {
        const float rn = v.x;
        scal[3] = rn / scal[0];
        scal[0] = rn;
    }
}

// b += alpha*p_old ; p = r + beta*p_old
__global__ void update_pb(float2* __restrict__ p, const float2* __restrict__ r,
                          float2* __restrict__ b, const float* __restrict__ scal) {
    const float ar = scal[1], ai = scal[2], beta = scal[3];
    const int e = blockIdx.x*256 + threadIdx.x;
    if (e < N2) {
        const float2 pv = p[e], rv = r[e];
        float2 bv = b[e];
        bv.x += ar*pv.x - ai*pv.y;
        bv.y += ar*pv.y + ai*pv.x;
        b[e] = bv;
        p[e] = make_float2(rv.x + beta*pv.x, rv.y + beta*pv.y);
    }
}

// final iteration fused: out = pack(b + alpha*p) — b itself is dead after this.
__global__ void final_bpack(const float2* __restrict__ b, const float2* __restrict__ p,
                            const float* __restrict__ scal, float* __restrict__ out) {
    const float ar = scal[1], ai = scal[2];
    const int e = blockIdx.x*256 + threadIdx.x;
    if (e >= 32*NPIX) return;
    const int pix = e >> 5;
    const int cc  = e & 31;
    const size_t idx = (size_t)(cc & 15)*NPIX + pix;
    const float2 pv = p[idx];
    const float2 bv = b[idx];
    out[e] = (cc < 16) ? (bv.x + ar*pv.x - ai*pv.y)
                       : (bv.y + ar*pv.y + ai*pv.x);
}

extern "C" void kernel_launch(void* const* d_in, const int* in_sizes, int n_in,
                              void* d_out, int out_size, void* d_ws, size_t ws_size,
                              hipStream_t stream) {
    const float* z    = (const float*)d_in[0];
    const float* ks   = (const float*)d_in[1];
    const float* kr   = (const float*)d_in[2];
    const float* ki   = (const float*)d_in[3];
    const float* prev = (const float*)d_in[5];
    const float* miu  = (const float*)d_in[6];
    float* out = (float*)d_out;

    char* w = (char*)d_ws;
    const size_t FB = (size_t)N2 * sizeof(float2);
    float2* wsf = (float2*)w; w += FB;    // b (in-place)
    float2* pf  = (float2*)w; w += FB;
    float2* rf  = (float2*)w; w += FB;
    float2* qf  = (float2*)w; w += FB;
    float2* tf  = (float2*)w; w += FB;
    u32* wbuf   = (u32*)w;   w += (size_t)2*162*256*sizeof(u32);   // 331776 B
    uint8_t* mask8 = (uint8_t*)w; w += (size_t)N2;
    w = (char*)(((uintptr_t)w + 255) & ~(uintptr_t)255);
    float2* partials = (float2*)w; w += (size_t)NCBLK * sizeof(float2);
    float*  scal     = (float*)w;

    const u32* wbF = wbuf;
    const u32* wbB = wbuf + (size_t)162*256;

    prep_weights<<<81, 256, 0, stream>>>(kr, ki, wbuf);
    prep_fields<<<576, 256, 0, stream>>>(ks, prev, wsf, mask8);

    conv9<0><<<NCBLK, 384, 0, stream>>>(wsf, wbF, tf, nullptr, nullptr, nullptr, nullptr, nullptr, nullptr, nullptr);
    conv9<2><<<NCBLK, 384, 0, stream>>>(tf, wbB, pf, rf, wsf, ks, z, mask8, miu, partials);
    finalize_rr<<<1, 256, 0, stream>>>(partials, scal, NCBLK);

    for (int it = 0; it < 10; ++it) {
        conv9<0><<<NCBLK, 384, 0, stream>>>(pf, wbF, tf, nullptr, nullptr, nullptr, nullptr, nullptr, nullptr, nullptr);
        conv9<1><<<NCBLK, 384, 0, stream>>>(tf, wbB, qf, nullptr, pf, nullptr, nullptr, mask8, miu, partials);
        finalize_alpha<<<1, 256, 0, stream>>>(partials, scal, NCBLK);
        if (it < 9) {
            update_r<<<NRED, 256, 0, stream>>>(rf, qf, scal, partials);
            finalize_beta<<<1, NRED, 0, stream>>>(partials, scal);
            update_pb<<<9216, 256, 0, stream>>>(pf, rf, wsf, scal);
        } else {
            final_bpack<<<18432, 256, 0, stream>>>(wsf, pf, scal, out);
        }
    }
}

// Round 21
// 1012.261 us; speedup vs baseline: 1.1874x; 1.0082x over previous
//
#include <hip/hip_runtime.h>
#include <stdint.h>

// SPIRiT CG reconstruction. Convs: single-product bf16 MFMA (W and X RN bf16),
// per-tap implicit GEMM M=16 c_out, N=16 pixels, K=32 = 16 c_in x {re,im}.
// R21 = R20 convs (best, 1020us) + scalar-kernel elimination: the 21
// single-block finalize kernels (latency bubbles ~4us each) are replaced by
// per-block redundant reductions of the tiny partials buffers inside
// update_r / update_pb / final_bpack (deterministic: identical data+order in
// every block). rr flows through ping-pong partials buffers, no scalar slots.
// update_pb/final run 2048-block grid-stride (G11).

#define MM 384
#define NPIX (MM*MM)          // 147456
#define N2 (16*NPIX)
#define NRED 512
#define NCBLK 768             // 32 row-tiles (12 rows) x 24 col-tiles (16 cols)
#define SWZ(c) (((c) >> 1) & 3)

typedef __attribute__((ext_vector_type(8))) short short8;
typedef __attribute__((ext_vector_type(4))) float f32x4;
typedef unsigned int u32;

__device__ __forceinline__ float2 block_reduce2(float2 v) {
    #pragma unroll
    for (int off = 32; off > 0; off >>= 1) {
        v.x += __shfl_down(v.x, off);
        v.y += __shfl_down(v.y, off);
    }
    __shared__ float2 tmp[8];
    const int wid = threadIdx.x >> 6, lid = threadIdx.x & 63;
    if (lid == 0) tmp[wid] = v;
    __syncthreads();
    if (threadIdx.x == 0) {
        const int nw = blockDim.x >> 6;
        for (int i = 1; i < nw; ++i) { v.x += tmp[i].x; v.y += tmp[i].y; }
    }
    return v;
}

__device__ __forceinline__ u32 bf16rn(float f) {   // round-to-nearest-even bf16
    const u32 u = __float_as_uint(f);
    return (u + 0x7FFFu + ((u >> 16) & 1u)) >> 16;
}

// Weight fragments (RN bf16): [dir][slot=q*9+p][hf][lane64][4 u32]  (q-major)
// hf=0 rows: [Wr | -Wi] (-> real), hf=1 rows: [Wi | Wr] (-> imag);
// lane = co + 16*kgroup. Tap block = 2 KB (1 KB per hf).
__global__ void prep_weights(const float* __restrict__ kr, const float* __restrict__ ki,
                             u32* __restrict__ wbuf) {
    const int e = blockIdx.x * 256 + threadIdx.x;
    if (e >= 20736) return;    // 2 dir x 81 tap x 2 hf x 64 lane
    const int lane = e & 63;
    int r = e >> 6;
    const int hf = r & 1; r >>= 1;
    const int q = r % 9; r /= 9;
    const int p = r % 9; r /= 9;
    const int dir = r;
    const int co = lane & 15, g = lane >> 4;
    float vv[8];
    #pragma unroll
    for (int t = 0; t < 8; ++t) {
        const int kc = 8 * g + t;
        const int ci = kc & 15;
        const int isI = kc >> 4;
        int sidx;
        if (dir == 0) sidx = (q*9 + p)*256 + ci*16 + co;          // Wf[co,ci,p,q]=K[q,p,ci,co]
        else          sidx = ((8-q)*9 + (8-p))*256 + co*16 + ci;  // Wb = conj flip swap
        const float wr = kr[sidx];
        const float wi = (dir == 0) ? ki[sidx] : -ki[sidx];
        vv[t] = (hf == 0) ? (isI ? -wi : wr) : (isI ? wr : wi);
    }
    u32 pk[4];
    #pragma unroll
    for (int t = 0; t < 4; ++t) pk[t] = bf16rn(vv[2*t]) | (bf16rn(vv[2*t+1]) << 16);
    u32* o = wbuf + (size_t)(dir*162 + (q*9 + p)*2 + hf)*256 + lane*4;
    *(uint4*)o = make_uint4(pk[0], pk[1], pk[2], pk[3]);
}

__global__ void prep_fields(const float* __restrict__ ks, const float* __restrict__ prev,
                            float2* __restrict__ wsf, uint8_t* __restrict__ mask8) {
    const int pix = blockIdx.x * blockDim.x + threadIdx.x;
    if (pix >= NPIX) return;
    #pragma unroll
    for (int c = 0; c < 16; ++c) {
        const float krr = ks[(size_t)pix*32 + c];
        const float kii = ks[(size_t)pix*32 + c + 16];
        mask8[(size_t)c*NPIX + pix] = (krr != 0.f || kii != 0.f) ? 1 : 0;
        wsf[(size_t)c*NPIX + pix] = make_float2(prev[(size_t)pix*32 + c], prev[(size_t)pix*32 + c + 16]);
    }
}

// MODE 0: out = conv(x) - x
// MODE 1: out = conv(x) - x + (mask+am)*aux ; partial += out*conj(aux)
// MODE 2: out=out2 = mask*kk + am*z - (conv(x)-x) - (mask+am)*aux ; partial += |out|^2
// Each wave handles ONE component (hf); all epilogue math is separable.
template<int MODE>
__global__ __launch_bounds__(384, 5)
void conv9(const float2* __restrict__ x, const u32* __restrict__ Wd,
           float2* __restrict__ out, float2* __restrict__ out2,
           const float2* __restrict__ aux, const float* __restrict__ ks,
           const float* __restrict__ z, const uint8_t* __restrict__ mask8,
           const float* __restrict__ miu, float2* __restrict__ partials)
{
    __shared__ __align__(16) char Xs[20*24*64];   // 30720 B
    const int t = threadIdx.x;
    const int bi0 = blockIdx.x;
    const int bi = (bi0 & 7) * 96 + (bi0 >> 3);   // XCD swizzle: 4-tile-row band/XCD
    const int i0 = (bi / 24) * 12;
    const int j0 = (bi % 24) * 16;
    const int w = t >> 6, lane = t & 63;
    const int hf = (w >= 3) ? 1 : 0;  // 0: real component, 1: imag component
    const int wr = w - 3*hf;          // row group (rows 4wr..4wr+3)
    const int m = lane & 15, g = lane >> 4;

    // ---- stage 20x24 slab (rows i0-4..i0+15, cols j0-4..j0+19), bf16 RN,
    //      64 B/px: 4 slots of 16B, content c stored at slot c ^ SWZ(col).
    for (int u = t; u < 20*24; u += 384) {
        const int col = u % 24, row = u / 24;
        const int row_g = i0 - 4 + row, col_g = j0 - 4 + col;
        const bool valid = ((unsigned)row_g < MM) && ((unsigned)col_g < MM);
        const float2* src = x + (size_t)row_g*MM + col_g;
        float2 v[16];
        #pragma unroll
        for (int ci = 0; ci < 16; ++ci)
            v[ci] = valid ? src[(size_t)ci*NPIX] : make_float2(0.f, 0.f);
        u32 c0[4], c1[4], c2[4], c3[4];
        #pragma unroll
        for (int j = 0; j < 4; ++j) {
            c0[j] = bf16rn(v[2*j].x)     | (bf16rn(v[2*j+1].x) << 16);
            c1[j] = bf16rn(v[8+2*j].x)   | (bf16rn(v[9+2*j].x) << 16);
            c2[j] = bf16rn(v[2*j].y)     | (bf16rn(v[2*j+1].y) << 16);
            c3[j] = bf16rn(v[8+2*j].y)   | (bf16rn(v[9+2*j].y) << 16);
        }
        const int k3 = SWZ(col);
        char* pb = Xs + (size_t)(row*24 + col)*64;
        *(uint4*)(pb + (((0 ^ k3)) << 4)) = make_uint4(c0[0], c0[1], c0[2], c0[3]);
        *(uint4*)(pb + (((1 ^ k3)) << 4)) = make_uint4(c1[0], c1[1], c1[2], c1[3]);
        *(uint4*)(pb + (((2 ^ k3)) << 4)) = make_uint4(c2[0], c2[1], c2[2], c2[3]);
        *(uint4*)(pb + (((3 ^ k3)) << 4)) = make_uint4(c3[0], c3[1], c3[2], c3[3]);
    }
    __syncthreads();

    f32x4 acc[4];
    #pragma unroll
    for (int a = 0; a < 4; ++a) acc[a] = (f32x4){0.f, 0.f, 0.f, 0.f};

    // ---- 81 taps, q-outer / p-inner (unrolled 9). X ring-6, W ring-9,
    //      compute-then-prefetch (R8 bug: reversed order clobbers the ring).
    const char* wl = (const char*)Wd + (lane << 4) + (hf << 10);
    short8 W0, W1, W2, W3, W4, W5, W6, W7, W8;
    short8 X0, X1, X2, X3, X4, X5;

    #define LW(WS, ADDR) do { WS = *(const short8*)(ADDR); } while (0)
    #define MFQ(Xa, Xb, Xc, Xd, WS) do { \
        acc[0] = __builtin_amdgcn_mfma_f32_16x16x32_bf16(WS, Xa, acc[0], 0, 0, 0); \
        acc[1] = __builtin_amdgcn_mfma_f32_16x16x32_bf16(WS, Xb, acc[1], 0, 0, 0); \
        acc[2] = __builtin_amdgcn_mfma_f32_16x16x32_bf16(WS, Xc, acc[2], 0, 0, 0); \
        acc[3] = __builtin_amdgcn_mfma_f32_16x16x32_bf16(WS, Xd, acc[3], 0, 0, 0); } while (0)

    LW(W0, wl);            LW(W1, wl + 2048);   LW(W2, wl + 4096);
    LW(W3, wl + 6144);     LW(W4, wl + 8192);   LW(W5, wl + 10240);
    LW(W6, wl + 12288);    LW(W7, wl + 14336);  LW(W8, wl + 16384);
    {
        const char* xb0 = Xs + (size_t)((4*wr)*24 + m)*64 + ((g ^ SWZ(m)) << 4);
        X0 = *(const short8*)(xb0);
        X1 = *(const short8*)(xb0 + 1536);
        X2 = *(const short8*)(xb0 + 2*1536);
        X3 = *(const short8*)(xb0 + 3*1536);
        X4 = *(const short8*)(xb0 + 4*1536);
    }

    #pragma unroll 1
    for (int qq = 0; qq < 9; ++qq) {
        const char* wq = wl + (size_t)qq * 18432 + 18432;   // next column taps
        const int colq = m + qq;
        const char* xb  = Xs + (size_t)((4*wr)*24 + colq)*64 + ((g ^ SWZ(colq)) << 4);
        const int colq1 = colq + 1;
        const char* xbn = Xs + (size_t)((4*wr)*24 + colq1)*64 + ((g ^ SWZ(colq1)) << 4);

        MFQ(X0, X1, X2, X3, W0); LW(W0, wq);           X5 = *(const short8*)(xb + 5*1536);   // p0
        MFQ(X1, X2, X3, X4, W1); LW(W1, wq + 2048);    X0 = *(const short8*)(xb + 6*1536);   // p1
        MFQ(X2, X3, X4, X5, W2); LW(W2, wq + 4096);    X1 = *(const short8*)(xb + 7*1536);   // p2
        MFQ(X3, X4, X5, X0, W3); LW(W3, wq + 6144);    X2 = *(const short8*)(xb + 8*1536);   // p3
        MFQ(X4, X5, X0, X1, W4); LW(W4, wq + 8192);    X3 = *(const short8*)(xb + 9*1536);   // p4
        MFQ(X5, X0, X1, X2, W5); LW(W5, wq + 10240);   X4 = *(const short8*)(xb + 10*1536);  // p5
        MFQ(X0, X1, X2, X3, W6); LW(W6, wq + 12288);   X5 = *(const short8*)(xb + 11*1536);  // p6
        MFQ(X1, X2, X3, X4, W7); LW(W7, wq + 14336);   X0 = *(const short8*)(xbn);           // p7
        MFQ(X2, X3, X4, X5, W8); LW(W8, wq + 16384);   X1 = *(const short8*)(xbn + 1536);    // p8
        X2 = *(const short8*)(xbn + 2*1536);
        X3 = *(const short8*)(xbn + 3*1536);
        X4 = *(const short8*)(xbn + 4*1536);
    }
    #undef LW
    #undef MFQ
    // (last column's W prefetches over-read ~18 KB past this dir's W region
    //  into the mask8 workspace buffer; values unused — harmless.)

    // ---- epilogue: C/D col = lane&15 = pixel col, row = g*4+j = co.
    //      This wave stores only component hf of each float2; cross-component
    //      dot terms are separable and summed in the block reduction.
    const float am = (MODE >= 1) ? fabsf(miu[0]) : 0.f;
    float2 part = make_float2(0.f, 0.f);
    const float* xf  = (const float*)x;
    const float* axf = (const float*)aux;
    float* of  = (float*)out;
    float* o2f = (float*)out2;
    #pragma unroll
    for (int r = 0; r < 4; ++r) {
        const int rowo = i0 + 4*wr + r;
        const int colo = j0 + m;
        const int pix = rowo*MM + colo;
        #pragma unroll
        for (int j = 0; j < 4; ++j) {
            const int co = g*4 + j;
            const size_t idx = (size_t)co*NPIX + pix;
            const float v = acc[r][j];
            if (MODE == 0) {
                of[2*idx + hf] = v - xf[2*idx + hf];
            } else if (MODE == 1) {
                const float tc = xf[2*idx + hf];
                const float2 pc = aux[idx];
                const float pc_c = hf ? pc.y : pc.x;
                const float mv = mask8[idx] ? 1.f : 0.f;
                const float qc = v - tc + (mv + am)*pc_c;
                of[2*idx + hf] = qc;
                // part = sum q*conj(p): re += qr*pr + qi*pi ; im += qi*pr - qr*pi
                part.x += qc * pc_c;
                part.y += hf ? qc * pc.x : -qc * pc.y;
            } else {
                const float tc = xf[2*idx + hf];
                const float wc = axf[2*idx + hf];
                const float mv = mask8[idx] ? 1.f : 0.f;
                const float kc = ks[(size_t)pix*32 + co + 16*hf];
                const float zc = z[(size_t)pix*32 + co + 16*hf];
                const float pc = mv*kc + am*zc - (v - tc) - (mv + am)*wc;
                of[2*idx + hf]  = pc;
                o2f[2*idx + hf] = pc;
                part.x += pc * pc;
            }
        }
    }
    if (MODE >= 1) {
        __syncthreads();
        part = block_reduce2(part);
        if (t == 0) partials[bi] = part;
    }
}

// r -= alpha*q ; bufRnew[blk] = |r|^2 partial. alpha computed per-block from
// bufQP (768, dot(q,p)) and bufRold (cntOld, |r_old|^2) — deterministic.
__global__ void update_r(float2* __restrict__ r, const float2* __restrict__ q,
                         const float2* __restrict__ bufQP,
                         const float2* __restrict__ bufRold, int cntOld,
                         float2* __restrict__ bufRnew) {
    float2 s1 = make_float2(0.f, 0.f);
    float rro = 0.f;
    for (int i = threadIdx.x; i < 768; i += 256) { s1.x += bufQP[i].x; s1.y += bufQP[i].y; }
    for (int i = threadIdx.x; i < cntOld; i += 256) rro += bufRold[i].x;
    s1 = block_reduce2(s1);
    __syncthreads();
    float2 s2 = block_reduce2(make_float2(rro, 0.f));
    __shared__ float2 ab;
    if (threadIdx.x == 0) {
        const float d = s1.x*s1.x + s1.y*s1.y;
        ab = make_float2(s2.x*s1.x/d, -s2.x*s1.y/d);
    }
    __syncthreads();
    const float ar = ab.x, ai = ab.y;
    float srr = 0.f;
    for (int e = blockIdx.x*256 + threadIdx.x; e < N2; e += NRED*256) {
        const float2 qv = q[e];
        float2 rv = r[e];
        rv.x -= ar*qv.x - ai*qv.y;
        rv.y -= ar*qv.y + ai*qv.x;
        r[e] = rv;
        srr += rv.x*rv.x + rv.y*rv.y;
    }
    __syncthreads();
    float2 s3 = block_reduce2(make_float2(srr, 0.f));
    if (threadIdx.x == 0) bufRnew[blockIdx.x] = make_float2(s3.x, 0.f);
}

// b += alpha*p_old ; p = r_new + beta*p_old. alpha/beta per-block from bufs.
__global__ void update_pb(float2* __restrict__ p, const float2* __restrict__ r,
                          float2* __restrict__ b,
                          const float2* __restrict__ bufQP,
                          const float2* __restrict__ bufRold, int cntOld,
                          const float2* __restrict__ bufRnew) {
    float2 s1 = make_float2(0.f, 0.f);
    float rro = 0.f, rrn = 0.f;
    for (int i = threadIdx.x; i < 768; i += 256) { s1.x += bufQP[i].x; s1.y += bufQP[i].y; }
    for (int i = threadIdx.x; i < cntOld; i += 256) rro += bufRold[i].x;
    for (int i = threadIdx.x; i < NRED; i += 256) rrn += bufRnew[i].x;
    s1 = block_reduce2(s1);
    __syncthreads();
    float2 s2 = block_reduce2(make_float2(rro, rrn));
    __shared__ float4 abb;
    if (threadIdx.x == 0) {
        const float d = s1.x*s1.x + s1.y*s1.y;
        abb = make_float4(s2.x*s1.x/d, -s2.x*s1.y/d, s2.y/s2.x, 0.f);
    }
    __syncthreads();
    const float ar = abb.x, ai = abb.y, beta = abb.z;
    for (int e = blockIdx.x*256 + threadIdx.x; e < N2; e += 2048*256) {
        const float2 pv = p[e], rv = r[e];
        float2 bv = b[e];
        bv.x += ar*pv.x - ai*pv.y;
        bv.y += ar*pv.y + ai*pv.x;
        b[e] = bv;
        p[e] = make_float2(rv.x + beta*pv.x, rv.y + beta*pv.y);
    }
}

// final iteration fused: out = pack(b + alpha*p). alpha per-block from bufs.
__global__ void final_bpack(const float2* __restrict__ b, const float2* __restrict__ p,
                            const float2* __restrict__ bufQP,
                            const float2* __restrict__ bufRold,
                            float* __restrict__ out) {
    float2 s1 = make_float2(0.f, 0.f);
    float rro = 0.f;
    for (int i = threadIdx.x; i < 768; i += 256) { s1.x += bufQP[i].x; s1.y += bufQP[i].y; }
    for (int i = threadIdx.x; i < NRED; i += 256) rro += bufRold[i].x;
    s1 = block_reduce2(s1);
    __syncthreads();
    float2 s2 = block_reduce2(make_float2(rro, 0.f));
    __shared__ float2 ab;
    if (threadIdx.x == 0) {
        const float d = s1.x*s1.x + s1.y*s1.y;
        ab = make_float2(s2.x*s1.x/d, -s2.x*s1.y/d);
    }
    __syncthreads();
    const float ar = ab.x, ai = ab.y;
    for (int e = blockIdx.x*256 + threadIdx.x; e < 32*NPIX; e += 2048*256) {
        const int pix = e >> 5;
        const int cc  = e & 31;
        const size_t idx = (size_t)(cc & 15)*NPIX + pix;
        const float2 pv = p[idx];
        const float2 bv = b[idx];
        out[e] = (cc < 16) ? (bv.x + ar*pv.x - ai*pv.y)
                           : (bv.y + ar*pv.y + ai*pv.x);
    }
}

extern "C" void kernel_launch(void* const* d_in, const int* in_sizes, int n_in,
                              void* d_out, int out_size, void* d_ws, size_t ws_size,
                              hipStream_t stream) {
    const float* z    = (const float*)d_in[0];
    const float* ks   = (const float*)d_in[1];
    const float* kr   = (const float*)d_in[2];
    const float* ki   = (const float*)d_in[3];
    const float* prev = (const float*)d_in[5];
    const float* miu  = (const float*)d_in[6];
    float* out = (float*)d_out;

    char* w = (char*)d_ws;
    const size_t FB = (size_t)N2 * sizeof(float2);
    float2* wsf = (float2*)w; w += FB;    // b (in-place)
    float2* pf  = (float2*)w; w += FB;
    float2* rf  = (float2*)w; w += FB;
    float2* qf  = (float2*)w; w += FB;
    float2* tf  = (float2*)w; w += FB;
    u32* wbuf   = (u32*)w;   w += (size_t)2*162*256*sizeof(u32);   // 331776 B
    uint8_t* mask8 = (uint8_t*)w; w += (size_t)N2;
    w = (char*)(((uintptr_t)w + 255) & ~(uintptr_t)255);
    float2* bufQP = (float2*)w; w += (size_t)NCBLK * sizeof(float2);
    float2* bufR0 = (float2*)w; w += (size_t)NCBLK * sizeof(float2);
    float2* bufR1 = (float2*)w; w += (size_t)NCBLK * sizeof(float2);

    const u32* wbF = wbuf;
    const u32* wbB = wbuf + (size_t)162*256;
    float2* bufR[2] = { bufR0, bufR1 };

    prep_weights<<<81, 256, 0, stream>>>(kr, ki, wbuf);
    prep_fields<<<576, 256, 0, stream>>>(ks, prev, wsf, mask8);

    // setup: t = (G-I) ws ; p0 = r0 = ... ; |r0|^2 partials -> bufR0 (768)
    conv9<0><<<NCBLK, 384, 0, stream>>>(wsf, wbF, tf, nullptr, nullptr, nullptr, nullptr, nullptr, nullptr, nullptr);
    conv9<2><<<NCBLK, 384, 0, stream>>>(tf, wbB, pf, rf, wsf, ks, z, mask8, miu, bufR0);

    for (int it = 0; it < 10; ++it) {
        conv9<0><<<NCBLK, 384, 0, stream>>>(pf, wbF, tf, nullptr, nullptr, nullptr, nullptr, nullptr, nullptr, nullptr);
        conv9<1><<<NCBLK, 384, 0, stream>>>(tf, wbB, qf, nullptr, pf, nullptr, nullptr, mask8, miu, bufQP);
        const int ridx = it & 1, widx = (it + 1) & 1;
        const int cntOld = (it == 0) ? NCBLK : NRED;
        if (it < 9) {
            update_r<<<NRED, 256, 0, stream>>>(rf, qf, bufQP, bufR[ridx], cntOld, bufR[widx]);
            update_pb<<<2048, 256, 0, stream>>>(pf, rf, wsf, bufQP, bufR[ridx], cntOld, bufR[widx]);
        } else {
            final_bpack<<<2048, 256, 0, stream>>>(wsf, pf, bufQP, bufR[ridx], out);
        }
    }
}